// Round 2
// baseline (9519.296 us; speedup 1.0000x reference)
//
#include <hip/hip_runtime.h>
#include <cmath>

#define T_STEPS 300
#define NBATCH  256
#define NNEUR   1024
#define BN      (NBATCH * NNEUR)

typedef _Float16 f16x8 __attribute__((ext_vector_type(8)));
typedef float    f32x4 __attribute__((ext_vector_type(4)));

// ---------------- persistent RNN kernel --------------------------------------------------
// 256 WGs x 256 threads, cooperative launch (co-residency guaranteed or launch fails).
// WG: group g = bid&15 (batch rows [16g,16g+16)), member m = bid>>4 (neuron cols
// [64m,64m+64)). Wave w: K range [256w, 256w+256).
// B frags (masked W slice, f16) live in VGPRs for the whole run (128 VGPR/lane).
// r_t is read from / written to the output buffer itself (it IS the output).
// Sync: per-(group,member,wave) monotonic flag; consumer wave polls only its 4 K-column
// producers' 16 flags (relaxed/agent + acquire fence); producer release-stores after
// its rows land. Per-step spin budget guarantees termination even if scheduling breaks.
__global__ void __launch_bounds__(256, 1)
rnn_persistent(const float* __restrict__ inp, const float* __restrict__ nz,
               const float* __restrict__ W, const float* __restrict__ bias,
               const void* __restrict__ mask, unsigned* flags, float* out) {
    const int bid  = blockIdx.x;
    const int g    = bid & 15;
    const int m    = bid >> 4;
    const int tid  = threadIdx.x;
    const int w    = tid >> 6;
    const int lane = tid & 63;
    const int l15  = lane & 15;
    const int lq   = lane >> 4;

    __shared__ __align__(16) float part[2][4][16][68]; // [buf][wave][row][col+pad] 34.8KB
    __shared__ float ldspad[11800];                    // +47.2KB -> LDS > 80KB -> 1 WG/CU
    if (bias[0] == 1234567.25f) ldspad[tid] = 1.f;     // keep ldspad allocated (never true)

    // ---- mask dtype detection (bool may arrive as u8 / i32 / f32), wave-local scan ----
    // i32 mask -> words in {0,1}. f32 mask -> {0, 0x3F800000}. u8 -> packed 0/1 bytes.
    unsigned mb = 0;
    {
        const unsigned* m32 = (const unsigned*)mask;
        for (int idx = lane; idx < 1024; idx += 64) {
            unsigned v = m32[idx];
            if (v == 0x3F800000u) mb |= 2u;
            else if (v > 1u)      mb |= 1u;
        }
    }
    const bool mask_f32 = __ballot(mb & 2u) != 0ull;
    const bool mask_u8  = !mask_f32 && (__ballot(mb & 1u) != 0ull);

    // ---- build resident B fragments: b-frag lane mapping n=l15(+16ns), k=32kk+8lq+j ----
    f16x8 bfr[4][8];
    #pragma unroll
    for (int ns = 0; ns < 4; ++ns) {
        const size_t rowbase = (size_t)(64 * m + 16 * ns + l15) * NNEUR + 256 * w + 8 * lq;
        #pragma unroll
        for (int kk = 0; kk < 8; ++kk) {
            const size_t i0 = rowbase + 32 * kk;
            f16x8 bv;
            #pragma unroll
            for (int j = 0; j < 8; ++j) {
                const size_t i = i0 + j;
                bool mv;
                if (mask_f32)     mv = ((const float*)mask)[i] != 0.0f;
                else if (mask_u8) mv = ((const unsigned char*)mask)[i] != 0;
                else              mv = ((const int*)mask)[i] != 0;
                bv[j] = (_Float16)(mv ? W[i] : 0.0f);
            }
            bfr[ns][kk] = bv;
        }
    }

    const int orow = tid >> 4;          // 0..15 within group rows (wave w owns rows 4w..4w+3)
    const int ocol = (tid & 15) << 2;   // 0..60 within member cols
    const int grow = 16 * g + orow;
    const int gcol = 64 * m + ocol;
    const float4 b4 = *(const float4*)(bias + gcol);

    float x0 = 0.f, x1 = 0.f, x2 = 0.f, x3 = 0.f;

    // publish r_0 = tanh(0) = 0
    *(float4*)(out + (size_t)grow * NNEUR + gcol) = make_float4(0.f, 0.f, 0.f, 0.f);
    if (lane == 0)
        __hip_atomic_store(&flags[(g << 6) + (m << 2) + w], 1u,
                           __ATOMIC_RELEASE, __HIP_MEMORY_SCOPE_AGENT);

    unsigned* myflags = flags + (g << 6) + (w << 4); // members 4w..4w+3, all 4 waves each

    for (int t = 0; t < T_STEPS; ++t) {
        // prefetch step-t drive terms (independent of r_t, overlap with the poll)
        const size_t io = (size_t)t * BN + (size_t)grow * NNEUR + gcol;
        const float4 in4 = *(const float4*)(inp + io);
        const float4 nz4 = *(const float4*)(nz + io);

        {   // wait for the 4 members producing our K columns (16 flags); relaxed polls
            const unsigned tgt = (unsigned)(t + 1);
            if (lane < 16) {
                int spin = 0;
                while (__hip_atomic_load(&myflags[lane], __ATOMIC_RELAXED,
                                         __HIP_MEMORY_SCOPE_AGENT) < tgt) {
                    __builtin_amdgcn_s_sleep(1);
                    if (++spin > (1 << 16)) break;   // failsafe: never hang
                }
            }
            __builtin_amdgcn_fence(__ATOMIC_ACQUIRE, "agent");
        }

        // ---- A fragments from r_t = out[t] (f32 -> f16); a-frag: row=l15, k=32kk+8lq+j ----
        f16x8 a[8];
        {
            const float* ab = out + (size_t)t * BN + (size_t)(16 * g + l15) * NNEUR
                              + 256 * w + 8 * lq;
            #pragma unroll
            for (int kk = 0; kk < 8; ++kk) {
                const float4 lo = *(const float4*)(ab + 32 * kk);
                const float4 hi = *(const float4*)(ab + 32 * kk + 4);
                f16x8 av;
                av[0] = (_Float16)lo.x; av[1] = (_Float16)lo.y;
                av[2] = (_Float16)lo.z; av[3] = (_Float16)lo.w;
                av[4] = (_Float16)hi.x; av[5] = (_Float16)hi.y;
                av[6] = (_Float16)hi.z; av[7] = (_Float16)hi.w;
                a[kk] = av;
            }
        }

        // ---- partial GEMM over this wave's K range: 4 N-subtiles x 8 K-steps ----
        f32x4 acc[4] = {};
        #pragma unroll
        for (int kk = 0; kk < 8; ++kk)
            #pragma unroll
            for (int ns = 0; ns < 4; ++ns)
                acc[ns] = __builtin_amdgcn_mfma_f32_16x16x32_f16(a[kk], bfr[ns][kk], acc[ns], 0, 0, 0);

        // ---- cross-wave K reduction via double-buffered LDS partials ----
        const int pb = t & 1;
        #pragma unroll
        for (int ns = 0; ns < 4; ++ns)
            #pragma unroll
            for (int r = 0; r < 4; ++r)   // C/D layout: col=l15 (+16ns), row=4*lq+r
                part[pb][w][(lq << 2) + r][(ns << 4) + l15] = acc[ns][r];

        __syncthreads();

        f32x4 s = *(const f32x4*)&part[pb][0][orow][ocol];
        #pragma unroll
        for (int wv = 1; wv < 4; ++wv)
            s += *(const f32x4*)&part[pb][wv][orow][ocol];

        // ---- Euler update (f32 state in registers) + publish r_{t+1} ----
        x0 = 0.9f * x0 + 0.1f * (s[0] + in4.x + b4.x) + 0.003f * nz4.x;
        x1 = 0.9f * x1 + 0.1f * (s[1] + in4.y + b4.y) + 0.003f * nz4.y;
        x2 = 0.9f * x2 + 0.1f * (s[2] + in4.z + b4.z) + 0.003f * nz4.z;
        x3 = 0.9f * x3 + 0.1f * (s[3] + in4.w + b4.w) + 0.003f * nz4.w;

        *(float4*)(out + (size_t)(t + 1) * BN + (size_t)grow * NNEUR + gcol)
            = make_float4(tanhf(x0), tanhf(x1), tanhf(x2), tanhf(x3));

        if (lane == 0)
            __hip_atomic_store(&flags[(g << 6) + (m << 2) + w], (unsigned)(t + 2),
                               __ATOMIC_RELEASE, __HIP_MEMORY_SCOPE_AGENT);
    }
}

extern "C" void kernel_launch(void* const* d_in, const int* in_sizes, int n_in,
                              void* d_out, int out_size, void* d_ws, size_t ws_size,
                              hipStream_t stream) {
    const float* inp  = (const float*)d_in[0];
    const float* nz   = (const float*)d_in[1];
    const float* W    = (const float*)d_in[2];
    const float* bias = (const float*)d_in[3];
    const void*  mask = d_in[4];
    float* out = (float*)d_out;

    unsigned* flags = (unsigned*)d_ws;                 // 1024 u32 (16 groups x 16 members x 4 waves)
    hipMemsetAsync(flags, 0, 4096, stream);            // reset flags every call (graph-safe)

    void* args[] = {(void*)&inp, (void*)&nz, (void*)&W, (void*)&bias,
                    (void*)&mask, (void*)&flags, (void*)&out};
    hipError_t e = hipLaunchCooperativeKernel((const void*)rnn_persistent,
                                              dim3(256), dim3(256), args, 0, stream);
    if (e != hipSuccess) {
        // fallback: plain launch (1 WG/CU via LDS footprint -> co-resident in practice;
        // per-step spin budget guarantees termination regardless)
        rnn_persistent<<<dim3(256), dim3(256), 0, stream>>>(inp, nz, W, bias, mask, flags, out);
    }
}

// Round 4
// 2243.755 us; speedup vs baseline: 4.2426x; 4.2426x over previous
//
#include <hip/hip_runtime.h>
#include <cmath>

#define T_STEPS 300
#define NBATCH  256
#define NNEUR   1024
#define BN      (NBATCH * NNEUR)

typedef _Float16 f16x8 __attribute__((ext_vector_type(8)));
typedef float    f32x4 __attribute__((ext_vector_type(4)));

// L2-bypass (sc0 sc1) primitives: commit at / read from the device coherence point (L3).
// No wbl2 / inv ops ever needed -> no per-step L2 flush storm.
// NOTE: asm "v" constraint requires ext_vector types, not the HIP float4 struct.
__device__ __forceinline__ void store_f4_bypass(float* p, f32x4 v) {
    asm volatile("global_store_dwordx4 %0, %1, off sc0 sc1" :: "v"(p), "v"(v) : "memory");
}
__device__ __forceinline__ f32x4 load_f4_bypass(const float* p) {
    f32x4 d;
    asm volatile("global_load_dwordx4 %0, %1, off sc0 sc1" : "=v"(d) : "v"(p));
    return d;
}

// ---------------- persistent RNN kernel --------------------------------------------------
// 256 WGs x 256 threads, cooperative launch. WG: group g = bid&15 (batch rows
// [16g,16g+16)), member m = bid>>4 (neuron cols [64m,64m+64)). Wave w: K range
// [256w,256w+256). B frags (masked W slice, f16) live in VGPRs for the whole run.
// r_t is exchanged through the output buffer with sc0sc1 stores/loads (L3-coherent,
// no L2 writeback/invalidate). Sync: per-(group,member,wave) monotonic flag written
// with sc0sc1 after an explicit vmcnt(0) drain of the r stores; consumers poll with
// sc0sc1 dword loads. Per-step spin budget guarantees termination.
__global__ void __launch_bounds__(256, 1)
rnn_persistent(const float* __restrict__ inp, const float* __restrict__ nz,
               const float* __restrict__ W, const float* __restrict__ bias,
               const void* __restrict__ mask, unsigned* flags, float* out) {
    const int bid  = blockIdx.x;
    const int g    = bid & 15;
    const int m    = bid >> 4;
    const int tid  = threadIdx.x;
    const int w    = tid >> 6;
    const int lane = tid & 63;
    const int l15  = lane & 15;
    const int lq   = lane >> 4;

    __shared__ __align__(16) float part[2][4][16][68]; // [buf][wave][row][col+pad] 34.8KB

    // ---- mask dtype detection (bool may arrive as u8 / i32 / f32), wave-local scan ----
    unsigned mb = 0;
    {
        const unsigned* m32 = (const unsigned*)mask;
        for (int idx = lane; idx < 1024; idx += 64) {
            unsigned v = m32[idx];
            if (v == 0x3F800000u) mb |= 2u;
            else if (v > 1u)      mb |= 1u;
        }
    }
    const bool mask_f32 = __ballot(mb & 2u) != 0ull;
    const bool mask_u8  = !mask_f32 && (__ballot(mb & 1u) != 0ull);

    // ---- build resident B fragments: b-frag lane mapping n=l15(+16ns), k=32kk+8lq+j ----
    f16x8 bfr[4][8];
    #pragma unroll
    for (int ns = 0; ns < 4; ++ns) {
        const size_t rowbase = (size_t)(64 * m + 16 * ns + l15) * NNEUR + 256 * w + 8 * lq;
        #pragma unroll
        for (int kk = 0; kk < 8; ++kk) {
            const size_t i0 = rowbase + 32 * kk;
            f16x8 bv;
            #pragma unroll
            for (int j = 0; j < 8; ++j) {
                const size_t i = i0 + j;
                bool mv;
                if (mask_f32)     mv = ((const float*)mask)[i] != 0.0f;
                else if (mask_u8) mv = ((const unsigned char*)mask)[i] != 0;
                else              mv = ((const int*)mask)[i] != 0;
                bv[j] = (_Float16)(mv ? W[i] : 0.0f);
            }
            bfr[ns][kk] = bv;
        }
    }

    const int orow = tid >> 4;          // 0..15 within group rows (wave w owns rows 4w..4w+3)
    const int ocol = (tid & 15) << 2;   // 0..60 within member cols
    const int grow = 16 * g + orow;
    const int gcol = 64 * m + ocol;
    const float4 b4 = *(const float4*)(bias + gcol);

    float x0 = 0.f, x1 = 0.f, x2 = 0.f, x3 = 0.f;

    unsigned* const myflag  = &flags[(g << 6) + (m << 2) + w];   // this wave's flag
    unsigned* const myflags = flags + (g << 6) + (w << 4);       // producers we wait on

    // publish r_0 = tanh(0) = 0 (bypass store), drain, then flag=1
    {
        f32x4 z = {0.f, 0.f, 0.f, 0.f};
        store_f4_bypass(out + (size_t)grow * NNEUR + gcol, z);
    }
    asm volatile("s_waitcnt vmcnt(0)" ::: "memory");
    __builtin_amdgcn_sched_barrier(0);
    if (lane == 0) {
        unsigned one = 1u;
        asm volatile("global_store_dword %0, %1, off sc0 sc1" :: "v"(myflag), "v"(one) : "memory");
    }

    for (int t = 0; t < T_STEPS; ++t) {
        // prefetch step-t drive terms (independent of r_t; latency hides under the poll)
        const size_t io = (size_t)t * BN + (size_t)grow * NNEUR + gcol;
        const float4 in4 = *(const float4*)(inp + io);
        const float4 nz4 = *(const float4*)(nz + io);

        {   // wait for the 4 members producing our K columns (16 flags); sc0sc1 polls
            const unsigned tgt = (unsigned)(t + 1);
            if (lane < 16) {
                const unsigned* fp = &myflags[lane];
                int spin = 0;
                unsigned v;
                do {
                    asm volatile("global_load_dword %0, %1, off sc0 sc1\n\t"
                                 "s_waitcnt vmcnt(0)" : "=v"(v) : "v"(fp));
                    if (v >= tgt) break;
                    __builtin_amdgcn_s_sleep(1);
                } while (++spin < (1 << 14));            // failsafe: never hang
            }
            __builtin_amdgcn_sched_barrier(0);
        }

        // ---- A fragments from r_t = out[t] (sc0sc1 batch load, one drain) ----
        f32x4 alo[8], ahi[8];
        {
            const float* ab = out + (size_t)t * BN + (size_t)(16 * g + l15) * NNEUR
                              + 256 * w + 8 * lq;
            #pragma unroll
            for (int kk = 0; kk < 8; ++kk) {
                alo[kk] = load_f4_bypass(ab + 32 * kk);
                ahi[kk] = load_f4_bypass(ab + 32 * kk + 4);
            }
        }
        asm volatile("s_waitcnt vmcnt(0)" ::: "memory");
        __builtin_amdgcn_sched_barrier(0);

        f16x8 a[8];
        #pragma unroll
        for (int kk = 0; kk < 8; ++kk) {
            f16x8 av;
            av[0] = (_Float16)alo[kk][0]; av[1] = (_Float16)alo[kk][1];
            av[2] = (_Float16)alo[kk][2]; av[3] = (_Float16)alo[kk][3];
            av[4] = (_Float16)ahi[kk][0]; av[5] = (_Float16)ahi[kk][1];
            av[6] = (_Float16)ahi[kk][2]; av[7] = (_Float16)ahi[kk][3];
            a[kk] = av;
        }

        // ---- partial GEMM over this wave's K range: 4 N-subtiles x 8 K-steps ----
        f32x4 acc[4] = {};
        #pragma unroll
        for (int kk = 0; kk < 8; ++kk)
            #pragma unroll
            for (int ns = 0; ns < 4; ++ns)
                acc[ns] = __builtin_amdgcn_mfma_f32_16x16x32_f16(a[kk], bfr[ns][kk], acc[ns], 0, 0, 0);

        // ---- cross-wave K reduction via double-buffered LDS partials ----
        const int pb = t & 1;
        #pragma unroll
        for (int ns = 0; ns < 4; ++ns)
            #pragma unroll
            for (int r = 0; r < 4; ++r)   // C/D layout: col=l15 (+16ns), row=4*lq+r
                part[pb][w][(lq << 2) + r][(ns << 4) + l15] = acc[ns][r];

        __syncthreads();

        f32x4 s = *(const f32x4*)&part[pb][0][orow][ocol];
        #pragma unroll
        for (int wv = 1; wv < 4; ++wv)
            s += *(const f32x4*)&part[pb][wv][orow][ocol];

        // ---- Euler update (f32 state in registers) + publish r_{t+1} ----
        x0 = 0.9f * x0 + 0.1f * (s[0] + in4.x + b4.x) + 0.003f * nz4.x;
        x1 = 0.9f * x1 + 0.1f * (s[1] + in4.y + b4.y) + 0.003f * nz4.y;
        x2 = 0.9f * x2 + 0.1f * (s[2] + in4.z + b4.z) + 0.003f * nz4.z;
        x3 = 0.9f * x3 + 0.1f * (s[3] + in4.w + b4.w) + 0.003f * nz4.w;

        {
            f32x4 rv = {tanhf(x0), tanhf(x1), tanhf(x2), tanhf(x3)};
            store_f4_bypass(out + (size_t)(t + 1) * BN + (size_t)grow * NNEUR + gcol, rv);
        }
        asm volatile("s_waitcnt vmcnt(0)" ::: "memory");
        __builtin_amdgcn_sched_barrier(0);
        if (lane == 0) {
            unsigned nv = (unsigned)(t + 2);
            asm volatile("global_store_dword %0, %1, off sc0 sc1" :: "v"(myflag), "v"(nv) : "memory");
        }
    }
}

extern "C" void kernel_launch(void* const* d_in, const int* in_sizes, int n_in,
                              void* d_out, int out_size, void* d_ws, size_t ws_size,
                              hipStream_t stream) {
    const float* inp  = (const float*)d_in[0];
    const float* nz   = (const float*)d_in[1];
    const float* W    = (const float*)d_in[2];
    const float* bias = (const float*)d_in[3];
    const void*  mask = d_in[4];
    float* out = (float*)d_out;

    unsigned* flags = (unsigned*)d_ws;                 // 1024 u32 (16 groups x 16 members x 4 waves)
    (void)hipMemsetAsync(flags, 0, 4096, stream);      // reset flags every call (graph-safe)

    void* args[] = {(void*)&inp, (void*)&nz, (void*)&W, (void*)&bias,
                    (void*)&mask, (void*)&flags, (void*)&out};
    hipError_t e = hipLaunchCooperativeKernel((const void*)rnn_persistent,
                                              dim3(256), dim3(256), args, 0, stream);
    if (e != hipSuccess) {
        // fallback: plain launch; per-step spin budget guarantees termination regardless
        rnn_persistent<<<dim3(256), dim3(256), 0, stream>>>(inp, nz, W, bias, mask, flags, out);
    }
}

// Round 7
// 1581.292 us; speedup vs baseline: 6.0199x; 1.4189x over previous
//
#include <hip/hip_runtime.h>
#include <cmath>

#define T_STEPS 300
#define NBATCH  256
#define NNEUR   1024
#define BN      (NBATCH * NNEUR)
#define RING_WORDS (NBATCH * NNEUR)   // one ring slot = 256x1024 u32 = 1 MiB

typedef _Float16 f16x8 __attribute__((ext_vector_type(8)));
typedef float    f32x4 __attribute__((ext_vector_type(4)));
typedef unsigned u32x4 __attribute__((ext_vector_type(4)));

// ---- device-scope primitives (commit at / read from the L3 coherence point) -----------
__device__ __forceinline__ void st_u4_dev(unsigned* p, u32x4 v) {
    asm volatile("global_store_dwordx4 %0, %1, off sc0 sc1" :: "v"(p), "v"(v) : "memory");
}
__device__ __forceinline__ u32x4 ld_u4_dev(const unsigned* p) {
    u32x4 d; asm volatile("global_load_dwordx4 %0, %1, off sc0 sc1" : "=v"(d) : "v"(p)); return d;
}
__device__ __forceinline__ void st_f4_dev(float* p, f32x4 v) {
    asm volatile("global_store_dwordx4 %0, %1, off sc0 sc1" :: "v"(p), "v"(v) : "memory");
}
__device__ __forceinline__ f32x4 ld_f4_dev(const float* p) {
    f32x4 d; asm volatile("global_load_dwordx4 %0, %1, off sc0 sc1" : "=v"(d) : "v"(p)); return d;
}
__device__ __forceinline__ void st_dw_dev(unsigned* p, unsigned v) {
    asm volatile("global_store_dword %0, %1, off sc0 sc1" :: "v"(p), "v"(v) : "memory");
}
__device__ __forceinline__ unsigned ld_dw_dev(const unsigned* p) {
    unsigned v;
    asm volatile("global_load_dword %0, %1, off sc0 sc1\n\ts_waitcnt vmcnt(0)"
                 : "=v"(v) : "v"(p) : "memory");
    return v;
}
__device__ __forceinline__ void drain_vm() {
    asm volatile("s_waitcnt vmcnt(0)" ::: "memory");
}

// ---- shared prologue helpers -----------------------------------------------------------
__device__ __forceinline__ void detect_mask(const void* mask, int lane,
                                            bool& mask_f32, bool& mask_u8) {
    unsigned mb = 0;
    const unsigned* m32 = (const unsigned*)mask;
    for (int idx = lane; idx < 1024; idx += 64) {
        unsigned v = m32[idx];
        if (v == 0x3F800000u) mb |= 2u;
        else if (v > 1u)      mb |= 1u;
    }
    mask_f32 = __ballot(mb & 2u) != 0ull;
    mask_u8  = !mask_f32 && (__ballot(mb & 1u) != 0ull);
}

__device__ __forceinline__ void build_bfr(const float* W, const void* mask,
                                          bool mask_f32, bool mask_u8,
                                          int m, int w, int l15, int lq, f16x8 bfr[4][8]) {
    #pragma unroll
    for (int ns = 0; ns < 4; ++ns) {
        const size_t rowbase = (size_t)(64 * m + 16 * ns + l15) * NNEUR + 256 * w + 8 * lq;
        #pragma unroll
        for (int kk = 0; kk < 8; ++kk) {
            const size_t i0 = rowbase + 32 * kk;
            f16x8 bv;
            #pragma unroll
            for (int j = 0; j < 8; ++j) {
                const size_t i = i0 + j;
                bool mv;
                if (mask_f32)     mv = ((const float*)mask)[i] != 0.0f;
                else if (mask_u8) mv = ((const unsigned char*)mask)[i] != 0;
                else              mv = ((const int*)mask)[i] != 0;
                bv[j] = (_Float16)(mv ? W[i] : 0.0f);
            }
            bfr[ns][kk] = bv;
        }
    }
}

// ================= FAST kernel: ordering-free tagged-ring exchange (needs 2MB ws) =======
// word = ((t+1)<<16) | f16bits(r_t); slot = (t+1)&1. Data+validity atomic in one dword:
// no drains, no flags, no release/acquire anywhere in the steady-state loop.
__global__ void __launch_bounds__(256, 1)
rnn_fast(const float* __restrict__ inp, const float* __restrict__ nz,
         const float* __restrict__ W, const float* __restrict__ bias,
         const void* __restrict__ mask, unsigned* ring, float* out) {
    const int bid  = blockIdx.x;
    const int g    = bid & 15;
    const int m    = bid >> 4;
    const int tid  = threadIdx.x;
    const int w    = tid >> 6;
    const int lane = tid & 63;
    const int l15  = lane & 15;
    const int lq   = lane >> 4;

    __shared__ __align__(16) float part[2][4][16][68];

    bool mask_f32, mask_u8;
    detect_mask(mask, lane, mask_f32, mask_u8);
    f16x8 bfr[4][8];
    build_bfr(W, mask, mask_f32, mask_u8, m, w, l15, lq, bfr);

    const int orow = tid >> 4;
    const int ocol = (tid & 15) << 2;
    const int grow = 16 * g + orow;
    const int gcol = 64 * m + ocol;
    const float4 b4 = *(const float4*)(bias + gcol);

    float x0 = 0.f, x1 = 0.f, x2 = 0.f, x3 = 0.f;

    // r_0 = tanh(0) = 0: out slice only; t=0 iteration skips the poll entirely.
    *(float4*)(out + (size_t)grow * NNEUR + gcol) = make_float4(0.f, 0.f, 0.f, 0.f);

    const unsigned* rbase = ring + (size_t)(16 * g + l15) * NNEUR + 256 * w + 8 * lq;
    unsigned* const wslot = ring + (size_t)grow * NNEUR + gcol;

    for (int t = 0; t < T_STEPS; ++t) {
        const size_t io = (size_t)t * BN + (size_t)grow * NNEUR + gcol;
        const float4 in4 = *(const float4*)(inp + io);
        const float4 nz4 = *(const float4*)(nz + io);

        f16x8 a[8];
        if (t > 0) {
            const unsigned tgt = (unsigned)(t + 1) << 16;
            const unsigned* rb = rbase + (size_t)((t + 1) & 1) * RING_WORDS;
            u32x4 wv[16];
            int budget = 1 << 13;
            for (;;) {
                #pragma unroll
                for (int kk = 0; kk < 8; ++kk) {
                    wv[2 * kk]     = ld_u4_dev(rb + 32 * kk);
                    wv[2 * kk + 1] = ld_u4_dev(rb + 32 * kk + 4);
                }
                drain_vm();
                unsigned bad = 0;
                #pragma unroll
                for (int i = 0; i < 16; ++i) {
                    const u32x4 x = wv[i] ^ tgt;      // hi16 == 0 iff fresh
                    bad |= (x[0] | x[1] | x[2] | x[3]) & 0xFFFF0000u;
                }
                if (__ballot(bad != 0u) == 0ull) break;
                if (--budget <= 0) break;             // failsafe: never hang
                __builtin_amdgcn_s_sleep(1);
            }
            #pragma unroll
            for (int kk = 0; kk < 8; ++kk) {
                const u32x4 lo = wv[2 * kk], hi = wv[2 * kk + 1];
                u32x4 p;
                p[0] = (lo[0] & 0xFFFFu) | (lo[1] << 16);
                p[1] = (lo[2] & 0xFFFFu) | (lo[3] << 16);
                p[2] = (hi[0] & 0xFFFFu) | (hi[1] << 16);
                p[3] = (hi[2] & 0xFFFFu) | (hi[3] << 16);
                a[kk] = __builtin_bit_cast(f16x8, p);
            }
        } else {
            #pragma unroll
            for (int kk = 0; kk < 8; ++kk) a[kk] = f16x8{};
        }

        f32x4 acc[4] = {};
        #pragma unroll
        for (int kk = 0; kk < 8; ++kk)
            #pragma unroll
            for (int ns = 0; ns < 4; ++ns)
                acc[ns] = __builtin_amdgcn_mfma_f32_16x16x32_f16(a[kk], bfr[ns][kk], acc[ns], 0, 0, 0);

        const int pb = t & 1;
        #pragma unroll
        for (int ns = 0; ns < 4; ++ns)
            #pragma unroll
            for (int r = 0; r < 4; ++r)
                part[pb][w][(lq << 2) + r][(ns << 4) + l15] = acc[ns][r];

        __syncthreads();

        f32x4 s = *(const f32x4*)&part[pb][0][orow][ocol];
        #pragma unroll
        for (int wv2 = 1; wv2 < 4; ++wv2)
            s += *(const f32x4*)&part[pb][wv2][orow][ocol];

        x0 = 0.9f * x0 + 0.1f * (s[0] + in4.x + b4.x) + 0.003f * nz4.x;
        x1 = 0.9f * x1 + 0.1f * (s[1] + in4.y + b4.y) + 0.003f * nz4.y;
        x2 = 0.9f * x2 + 0.1f * (s[2] + in4.z + b4.z) + 0.003f * nz4.z;
        x3 = 0.9f * x3 + 0.1f * (s[3] + in4.w + b4.w) + 0.003f * nz4.w;

        const float r0 = tanhf(x0), r1 = tanhf(x1), r2 = tanhf(x2), r3 = tanhf(x3);

        *(float4*)(out + (size_t)(t + 1) * BN + (size_t)grow * NNEUR + gcol)
            = make_float4(r0, r1, r2, r3);

        {   // fire-and-forget tagged publish
            const unsigned tg = (unsigned)(t + 2) << 16;
            u32x4 pv;
            pv[0] = tg | (unsigned)__builtin_bit_cast(unsigned short, (_Float16)r0);
            pv[1] = tg | (unsigned)__builtin_bit_cast(unsigned short, (_Float16)r1);
            pv[2] = tg | (unsigned)__builtin_bit_cast(unsigned short, (_Float16)r2);
            pv[3] = tg | (unsigned)__builtin_bit_cast(unsigned short, (_Float16)r3);
            st_u4_dev(wslot + (size_t)((t + 2) & 1) * RING_WORDS, pv);
        }
    }
}

// ================= SLOW kernel: R4-proven sc0sc1 + flags (4KB ws footprint) =============
__global__ void __launch_bounds__(256, 1)
rnn_slow(const float* __restrict__ inp, const float* __restrict__ nz,
         const float* __restrict__ W, const float* __restrict__ bias,
         const void* __restrict__ mask, unsigned* flags, float* out) {
    const int bid  = blockIdx.x;
    const int g    = bid & 15;
    const int m    = bid >> 4;
    const int tid  = threadIdx.x;
    const int w    = tid >> 6;
    const int lane = tid & 63;
    const int l15  = lane & 15;
    const int lq   = lane >> 4;

    __shared__ __align__(16) float part[2][4][16][68];

    bool mask_f32, mask_u8;
    detect_mask(mask, lane, mask_f32, mask_u8);
    f16x8 bfr[4][8];
    build_bfr(W, mask, mask_f32, mask_u8, m, w, l15, lq, bfr);

    const int orow = tid >> 4;
    const int ocol = (tid & 15) << 2;
    const int grow = 16 * g + orow;
    const int gcol = 64 * m + ocol;
    const float4 b4 = *(const float4*)(bias + gcol);

    float x0 = 0.f, x1 = 0.f, x2 = 0.f, x3 = 0.f;

    unsigned* const myflag  = &flags[(g << 6) + (m << 2) + w];
    unsigned* const myflags = flags + (g << 6) + (w << 4);

    {
        f32x4 z = {0.f, 0.f, 0.f, 0.f};
        st_f4_dev(out + (size_t)grow * NNEUR + gcol, z);
    }
    drain_vm();
    __builtin_amdgcn_sched_barrier(0);
    if (lane == 0) st_dw_dev(myflag, 1u);

    for (int t = 0; t < T_STEPS; ++t) {
        const size_t io = (size_t)t * BN + (size_t)grow * NNEUR + gcol;
        const float4 in4 = *(const float4*)(inp + io);
        const float4 nz4 = *(const float4*)(nz + io);

        {
            const unsigned tgt = (unsigned)(t + 1);
            if (lane < 16) {
                const unsigned* fp = &myflags[lane];
                int spin = 0;
                unsigned v;
                do {
                    v = ld_dw_dev(fp);
                    if (v >= tgt) break;
                    __builtin_amdgcn_s_sleep(1);
                } while (++spin < (1 << 14));
            }
            __builtin_amdgcn_sched_barrier(0);
        }

        f32x4 alo[8], ahi[8];
        {
            const float* ab = out + (size_t)t * BN + (size_t)(16 * g + l15) * NNEUR
                              + 256 * w + 8 * lq;
            #pragma unroll
            for (int kk = 0; kk < 8; ++kk) {
                alo[kk] = ld_f4_dev(ab + 32 * kk);
                ahi[kk] = ld_f4_dev(ab + 32 * kk + 4);
            }
        }
        drain_vm();
        __builtin_amdgcn_sched_barrier(0);

        f16x8 a[8];
        #pragma unroll
        for (int kk = 0; kk < 8; ++kk) {
            f16x8 av;
            av[0] = (_Float16)alo[kk][0]; av[1] = (_Float16)alo[kk][1];
            av[2] = (_Float16)alo[kk][2]; av[3] = (_Float16)alo[kk][3];
            av[4] = (_Float16)ahi[kk][0]; av[5] = (_Float16)ahi[kk][1];
            av[6] = (_Float16)ahi[kk][2]; av[7] = (_Float16)ahi[kk][3];
            a[kk] = av;
        }

        f32x4 acc[4] = {};
        #pragma unroll
        for (int kk = 0; kk < 8; ++kk)
            #pragma unroll
            for (int ns = 0; ns < 4; ++ns)
                acc[ns] = __builtin_amdgcn_mfma_f32_16x16x32_f16(a[kk], bfr[ns][kk], acc[ns], 0, 0, 0);

        const int pb = t & 1;
        #pragma unroll
        for (int ns = 0; ns < 4; ++ns)
            #pragma unroll
            for (int r = 0; r < 4; ++r)
                part[pb][w][(lq << 2) + r][(ns << 4) + l15] = acc[ns][r];

        __syncthreads();

        f32x4 s = *(const f32x4*)&part[pb][0][orow][ocol];
        #pragma unroll
        for (int wv = 1; wv < 4; ++wv)
            s += *(const f32x4*)&part[pb][wv][orow][ocol];

        x0 = 0.9f * x0 + 0.1f * (s[0] + in4.x + b4.x) + 0.003f * nz4.x;
        x1 = 0.9f * x1 + 0.1f * (s[1] + in4.y + b4.y) + 0.003f * nz4.y;
        x2 = 0.9f * x2 + 0.1f * (s[2] + in4.z + b4.z) + 0.003f * nz4.z;
        x3 = 0.9f * x3 + 0.1f * (s[3] + in4.w + b4.w) + 0.003f * nz4.w;

        {
            f32x4 rv = {tanhf(x0), tanhf(x1), tanhf(x2), tanhf(x3)};
            st_f4_dev(out + (size_t)(t + 1) * BN + (size_t)grow * NNEUR + gcol, rv);
        }
        drain_vm();
        __builtin_amdgcn_sched_barrier(0);
        if (lane == 0) st_dw_dev(myflag, (unsigned)(t + 2));
    }
}

extern "C" void kernel_launch(void* const* d_in, const int* in_sizes, int n_in,
                              void* d_out, int out_size, void* d_ws, size_t ws_size,
                              hipStream_t stream) {
    const float* inp  = (const float*)d_in[0];
    const float* nz   = (const float*)d_in[1];
    const float* W    = (const float*)d_in[2];
    const float* bias = (const float*)d_in[3];
    const void*  mask = d_in[4];
    float* out = (float*)d_out;

    const size_t ring_bytes = (size_t)2 * RING_WORDS * sizeof(unsigned);  // 2 MiB
    unsigned* ws = (unsigned*)d_ws;

    if (ws_size >= ring_bytes) {
        // FAST path: tagged ring. Zero it every call (exact-match tags repeat across calls).
        (void)hipMemsetAsync(ws, 0, ring_bytes, stream);
        void* args[] = {(void*)&inp, (void*)&nz, (void*)&W, (void*)&bias,
                        (void*)&mask, (void*)&ws, (void*)&out};
        hipError_t e = hipLaunchCooperativeKernel((const void*)rnn_fast,
                                                  dim3(256), dim3(256), args, 0, stream);
        if (e != hipSuccess)
            rnn_fast<<<dim3(256), dim3(256), 0, stream>>>(inp, nz, W, bias, mask, ws, out);
    } else {
        // SLOW path (proven R4): flags only, 4 KiB.
        (void)hipMemsetAsync(ws, 0, 4096, stream);
        void* args[] = {(void*)&inp, (void*)&nz, (void*)&W, (void*)&bias,
                        (void*)&mask, (void*)&ws, (void*)&out};
        hipError_t e = hipLaunchCooperativeKernel((const void*)rnn_slow,
                                                  dim3(256), dim3(256), args, 0, stream);
        if (e != hipSuccess)
            rnn_slow<<<dim3(256), dim3(256), 0, stream>>>(inp, nz, W, bias, mask, ws, out);
    }
}